// Round 17
// baseline (298.411 us; speedup 1.0000x reference)
//
#include <hip/hip_runtime.h>
#include <hip/hip_bf16.h>

#define DIMV 64
#define CH 64
#define EPSB 1e-3f

using bf16x8 = __attribute__((ext_vector_type(8))) short;
using f32x16 = __attribute__((ext_vector_type(16))) float;

__device__ __forceinline__ unsigned short f2bf(float f) {
    union { float f; unsigned u; } x; x.f = f;
    unsigned r = x.u + 0x7fff + ((x.u >> 16) & 1);   // round-to-nearest-even
    return (unsigned short)(r >> 16);
}
__device__ __forceinline__ float bf2f(unsigned short u) {
    union { unsigned u; float f; } x; x.u = ((unsigned)u) << 16;
    return x.f;
}

__global__ void scatter_kernel(const float* __restrict__ x, const int* __restrict__ idx,
                               float* __restrict__ grid, int n_total) {
    int tid = blockIdx.x * blockDim.x + threadIdx.x;
    if (tid >= n_total) return;
    int n = tid >> 6, c = tid & 63;
    int ix = idx[n * 3 + 0], iy = idx[n * 3 + 1], iz = idx[n * 3 + 2];
    atomicAdd(&grid[(size_t)(((ix * DIMV) + iy) * DIMV + iz) * CH + c], x[tid]);
}

// ---------------- pack: fp32 grid * inv -> bf16 grid ----------------
__global__ void pack_kernel(const float* __restrict__ A, const float* __restrict__ inv,
                            unsigned short* __restrict__ G1) {
    int t = blockIdx.x * 256 + threadIdx.x;
    if (t >= (DIMV * DIMV * DIMV * CH) / 8) return;
    int v = t >> 3, c8 = (t & 7) * 8;
    const float* src = A + (size_t)v * CH + c8;
    float s = inv[v];
    __align__(16) unsigned short tmp[8];
#pragma unroll
    for (int j = 0; j < 8; ++j) tmp[j] = f2bf(src[j] * s);
    *(int4*)(G1 + (size_t)t * 8) = *(const int4*)tmp;
}

// ---------------- merged weight repack (k1, k2, w_mlp) into MFMA B-fragment layout ----------------
__global__ void wprep_all(const float* __restrict__ K1, const float* __restrict__ K2,
                          const float* __restrict__ Wm, unsigned short* __restrict__ wbuf1,
                          unsigned short* __restrict__ wbuf2, unsigned short* __restrict__ wm) {
    int t = blockIdx.x * 256 + threadIdx.x;
    if (t >= 2 * 110592 + 4096) return;
    const float* src;
    unsigned short* dst;
    int tt;
    if (t < 110592) { src = K1; dst = wbuf1; tt = t; }
    else if (t < 221184) { src = K2; dst = wbuf2; tt = t - 110592; }
    else { src = Wm; dst = wm; tt = t - 221184; }
    int j = tt & 7;
    int l = (tt >> 3) & 63;
    int nt = (tt >> 9) & 1;
    int kkl = (tt >> 10) & 3;
    int d = tt >> 12;                 // 0 for the mlp case
    int ci = kkl * 16 + (l >> 5) * 8 + j;
    int co = nt * 32 + (l & 31);
    dst[tt] = f2bf(src[((size_t)d * 64 + ci) * 64 + co]);
}

// ---------------- MFMA conv v10: 2x2x32 tile, 4 waves, wave = col x BOTH nt ----------------
// Slab 69632 B -> 2 blocks/CU (r15's occupancy mode). Wave w = xy-col (cx=w>>1, cy=w&1),
// covers 32z x 64co. Per d-step: 4 A ds_reads + 8 B loads -> 8 MFMAs (0.5 reads/MFMA,
// r6's reuse ratio; r15 was 1.0). Halves the LDS-pipe term of the serial sum at
// unchanged B-L1 / MFMA / stage terms. Inline r15 addressing (r16's hoist regressed).
// No barriers after stage, no sched intrinsics.
__global__ __launch_bounds__(256) void conv_mfma(
    const unsigned short* __restrict__ G, const unsigned short* __restrict__ wbuf,
    const float* __restrict__ cb, const float* __restrict__ g,
    const float* __restrict__ be, const float* __restrict__ m,
    const float* __restrict__ v, unsigned short* __restrict__ out) {
    __shared__ __align__(16) unsigned short slab[272 * 128];   // 69632 B
    const int tid = threadIdx.x;
    const int lane = tid & 63;
    const int w = tid >> 6;          // wave 0..3 = xy-col
    const int cx = (w >> 1) & 1;
    const int cy = w & 1;
    const int lz = lane & 31;
    const int kg = lane >> 5;
    const int BX = blockIdx.x, BY = blockIdx.y, BZ = blockIdx.z;
    const int x0 = 2 * BX - 1, y0 = 2 * BY - 1;
    const int zbase = 32 * BZ - 1;   // odd

    // Stage A slab: 4352 chunks of 16B, 17/thread. Pre-swizzled global source,
    // linear LDS write. Slot s at row (col,zp) holds ch-pair chunk cp = s ^ (zp&15).
#pragma unroll
    for (int it = 0; it < 17; ++it) {
        int idx = it * 256 + tid;           // 0..4351
        int s = idx & 15;
        int r = idx >> 4;                   // 0..271
        int zp = r % 17;
        int rxy = r / 17;                   // 0..15
        int xx = x0 + (rxy >> 2);
        int yy = y0 + (rxy & 3);
        int cp = s ^ (zp & 15);
        int c = cp >> 1, p = cp & 1;
        int zz = zbase + 2 * zp + p;
        int4 val = make_int4(0, 0, 0, 0);
        if ((unsigned)xx < DIMV && (unsigned)yy < DIMV && (unsigned)zz < DIMV)
            val = *(const int4*)(G + (size_t)(((xx * DIMV) + yy) * DIMV + zz) * CH + c * 8);
        *(int4*)(slab + (size_t)idx * 8) = val;
    }
    __syncthreads();

    f32x16 acc[2];
#pragma unroll
    for (int nt = 0; nt < 2; ++nt)
#pragma unroll
        for (int r = 0; r < 16; ++r) acc[nt][r] = 0.f;

    // B ping-pong prefetch: frag q = kkl*2+nt at wbuf + d*4096 + q*512 + lane*8
    const unsigned short* wlane = wbuf + lane * 8;
    bf16x8 bfr0[8], bfr1[8];
#pragma unroll
    for (int q = 0; q < 8; ++q)
        bfr0[q] = *(const bf16x8*)(wlane + q * 512);

#pragma unroll
    for (int d = 0; d < 27; ++d) {
        if (d < 26) {
            const unsigned short* wn = wlane + (size_t)(d + 1) * 4096;
            if (d & 1) {
#pragma unroll
                for (int q = 0; q < 8; ++q) bfr0[q] = *(const bf16x8*)(wn + q * 512);
            } else {
#pragma unroll
                for (int q = 0; q < 8; ++q) bfr1[q] = *(const bf16x8*)(wn + q * 512);
            }
        }
        const int dx = d / 9, dy = (d / 3) % 3, dz = d % 3;
        const int zval = lz + dz;                  // 0..33
        const int zp = zval >> 1, p = zval & 1;
        const int rbase = ((cx + dx) * 4 + (cy + dy)) * 17 + zp;
#pragma unroll
        for (int kkl = 0; kkl < 4; ++kkl) {
            const int c = kkl * 2 + kg;
            const int slot = (c * 2 + p) ^ (zp & 15);
            bf16x8 a = *(const bf16x8*)(slab + rbase * 128 + slot * 8);
            bf16x8 b0 = (d & 1) ? bfr1[kkl * 2 + 0] : bfr0[kkl * 2 + 0];
            bf16x8 b1 = (d & 1) ? bfr1[kkl * 2 + 1] : bfr0[kkl * 2 + 1];
            acc[0] = __builtin_amdgcn_mfma_f32_32x32x16_bf16(a, b0, acc[0], 0, 0, 0);
            acc[1] = __builtin_amdgcn_mfma_f32_32x32x16_bf16(a, b1, acc[1], 0, 0, 0);
        }
    }

    const int x_out = 2 * BX + cx;
    const int y_out = 2 * BY + cy;
#pragma unroll
    for (int nt = 0; nt < 2; ++nt) {
        int co = nt * 32 + lz;
        float scale = g[co] * rsqrtf(v[co] + EPSB);
        float shift = be[co] - m[co] * scale;
        float bias = cb[co];
        size_t base = (size_t)((x_out * DIMV) + y_out) * DIMV * CH + co;
#pragma unroll
        for (int r = 0; r < 16; ++r) {
            int zrow = (r & 3) + 8 * (r >> 2) + 4 * kg;
            int z = BZ * 32 + zrow;
            float val = fmaxf(acc[nt][r] + bias, 0.f) * scale + shift;
            out[base + (size_t)z * CH] = f2bf(val);
        }
    }
}

// ---------------- fused point-MLP (MFMA) + trilinear gather + final write ----------------
__global__ __launch_bounds__(256) void mlp_gather(
    const float* __restrict__ x, const unsigned short* __restrict__ wfrag,
    const float* __restrict__ b, const float* __restrict__ g,
    const float* __restrict__ be, const float* __restrict__ m,
    const float* __restrict__ v, const unsigned short* __restrict__ grid,
    const float* __restrict__ pts, float* __restrict__ out, int npts) {
    __shared__ float lds[128 * 64];          // 32 KB
    const int w = threadIdx.x >> 6;
    const int lane = threadIdx.x & 63;
    const int col = lane & 31;
    const int kg = lane >> 5;
    const int p0 = (blockIdx.x * 4 + w) * 32;

    if (p0 < npts) {
        bf16x8 a[4];
        const float* xr = x + (size_t)(p0 + col) * CH + kg * 8;
#pragma unroll
        for (int kk = 0; kk < 4; ++kk) {
            const float* p = xr + kk * 16;
            bf16x8 t;
#pragma unroll
            for (int j = 0; j < 8; ++j) t[j] = (short)f2bf(p[j]);
            a[kk] = t;
        }
        f32x16 acc[2];
#pragma unroll
        for (int nt = 0; nt < 2; ++nt)
#pragma unroll
            for (int r = 0; r < 16; ++r) acc[nt][r] = 0.f;
#pragma unroll
        for (int kk = 0; kk < 4; ++kk) {
            bf16x8 b0 = *(const bf16x8*)(wfrag + (kk * 2 + 0) * 512 + lane * 8);
            bf16x8 b1 = *(const bf16x8*)(wfrag + (kk * 2 + 1) * 512 + lane * 8);
            acc[0] = __builtin_amdgcn_mfma_f32_32x32x16_bf16(a[kk], b0, acc[0], 0, 0, 0);
            acc[1] = __builtin_amdgcn_mfma_f32_32x32x16_bf16(a[kk], b1, acc[1], 0, 0, 0);
        }
#pragma unroll
        for (int nt = 0; nt < 2; ++nt) {
            int co = nt * 32 + col;
            float scale = g[co] * rsqrtf(v[co] + EPSB);
            float shift = be[co] - m[co] * scale;
            float bias = b[co];
#pragma unroll
            for (int r = 0; r < 16; ++r) {
                int row = (r & 3) + 8 * (r >> 2) + 4 * kg;
                float val = fmaxf(acc[nt][r] + bias, 0.f) * scale + shift;
                lds[(w * 32 + row) * 64 + co] = val;
            }
        }
    }
    __syncthreads();

    const int pblk = blockIdx.x * 128;
#pragma unroll 4
    for (int i = 0; i < 32; ++i) {
        int idx = i * 256 + threadIdx.x;
        int pl = idx >> 6;
        int c = idx & 63;
        int pt = pblk + pl;
        if (pt >= npts) break;
        float px = fminf(fmaxf(pts[pt * 3 + 0], 0.f), (float)(DIMV - 1));
        float py = fminf(fmaxf(pts[pt * 3 + 1], 0.f), (float)(DIMV - 1));
        float pz = fminf(fmaxf(pts[pt * 3 + 2], 0.f), (float)(DIMV - 1));
        float fx = floorf(px), fy = floorf(py), fz = floorf(pz);
        float tx = px - fx, ty = py - fy, tz = pz - fz;
        int x0 = (int)fx, y0 = (int)fy, z0 = (int)fz;
        int x1 = min(x0 + 1, DIMV - 1), y1 = min(y0 + 1, DIMV - 1), z1 = min(z0 + 1, DIMV - 1);
        float wx0 = 1.f - tx, wy0 = 1.f - ty, wz0 = 1.f - tz;
        float acc = lds[pl * 64 + c];
        acc = fmaf(wx0 * wy0 * wz0, bf2f(grid[(size_t)(((x0 * DIMV) + y0) * DIMV + z0) * CH + c]), acc);
        acc = fmaf(wx0 * wy0 * tz,  bf2f(grid[(size_t)(((x0 * DIMV) + y0) * DIMV + z1) * CH + c]), acc);
        acc = fmaf(wx0 * ty * wz0,  bf2f(grid[(size_t)(((x0 * DIMV) + y1) * DIMV + z0) * CH + c]), acc);
        acc = fmaf(wx0 * ty * tz,   bf2f(grid[(size_t)(((x0 * DIMV) + y1) * DIMV + z1) * CH + c]), acc);
        acc = fmaf(tx * wy0 * wz0,  bf2f(grid[(size_t)(((x1 * DIMV) + y0) * DIMV + z0) * CH + c]), acc);
        acc = fmaf(tx * wy0 * tz,   bf2f(grid[(size_t)(((x1 * DIMV) + y0) * DIMV + z1) * CH + c]), acc);
        acc = fmaf(tx * ty * wz0,   bf2f(grid[(size_t)(((x1 * DIMV) + y1) * DIMV + z0) * CH + c]), acc);
        acc = fmaf(tx * ty * tz,    bf2f(grid[(size_t)(((x1 * DIMV) + y1) * DIMV + z1) * CH + c]), acc);
        out[(size_t)pt * CH + c] = acc;
    }
}

extern "C" void kernel_launch(void* const* d_in, const int* in_sizes, int n_in,
                              void* d_out, int out_size, void* d_ws, size_t ws_size,
                              hipStream_t stream) {
    const float* inputs = (const float*)d_in[0];
    const float* pt_coords = (const float*)d_in[1];
    const int* voxel_indexes = (const int*)d_in[2];
    const float* ppvi = (const float*)d_in[3];
    const float* w_mlp = (const float*)d_in[4];
    const float* b_mlp = (const float*)d_in[5];
    const float* g0 = (const float*)d_in[6];
    const float* be0 = (const float*)d_in[7];
    const float* m0 = (const float*)d_in[8];
    const float* v0 = (const float*)d_in[9];
    const float* k1 = (const float*)d_in[10];
    const float* cb1 = (const float*)d_in[11];
    const float* g1 = (const float*)d_in[12];
    const float* be1 = (const float*)d_in[13];
    const float* m1 = (const float*)d_in[14];
    const float* v1 = (const float*)d_in[15];
    const float* k2 = (const float*)d_in[16];
    const float* cb2 = (const float*)d_in[17];
    const float* g2 = (const float*)d_in[18];
    const float* be2 = (const float*)d_in[19];
    const float* m2 = (const float*)d_in[20];
    const float* v2 = (const float*)d_in[21];
    float* out = (float*)d_out;

    char* ws = (char*)d_ws;
    // [0, 67.1M):     A fp32 scatter grid; reused after pack: G2 bf16 [0,33.5M), G3 bf16 [33.5M,67.1M)
    // [67.1M,100.7M): G1 bf16 (pack output, conv1 input)
    // [100.7M, +):    wbuf1, wbuf2 (221184 B each), wmlp (8192 B)
    float* A = (float*)ws;
    unsigned short* G2 = (unsigned short*)ws;
    unsigned short* G3 = (unsigned short*)(ws + 33554432);
    unsigned short* G1 = (unsigned short*)(ws + 67108864);
    unsigned short* wbuf1 = (unsigned short*)(ws + 100663296);
    unsigned short* wbuf2 = (unsigned short*)(ws + 100884480);
    unsigned short* wmlp = (unsigned short*)(ws + 101105664);

    const int n_total = in_sizes[0];           // N * C
    const int npts = n_total / CH;
    const int nblk = (n_total + 255) / 256;
    const size_t grid_elems = (size_t)DIMV * DIMV * DIMV * CH;

    hipMemsetAsync(A, 0, grid_elems * sizeof(float), stream);
    wprep_all<<<880, 256, 0, stream>>>(k1, k2, w_mlp, wbuf1, wbuf2, wmlp);
    scatter_kernel<<<nblk, 256, 0, stream>>>(inputs, voxel_indexes, A, n_total);
    pack_kernel<<<(int)(grid_elems / 8 + 255) / 256, 256, 0, stream>>>(A, ppvi, G1);

    dim3 cgrid(32, 32, 2);
    conv_mfma<<<cgrid, 256, 0, stream>>>(G1, wbuf1, cb1, g1, be1, m1, v1, G2);
    conv_mfma<<<cgrid, 256, 0, stream>>>(G2, wbuf2, cb2, g2, be2, m2, v2, G3);

    mlp_gather<<<(npts + 127) / 128, 256, 0, stream>>>(
        inputs, wmlp, b_mlp, g0, be0, m0, v0, G3, pt_coords, out, npts);
}

// Round 18
// 253.151 us; speedup vs baseline: 1.1788x; 1.1788x over previous
//
#include <hip/hip_runtime.h>
#include <hip/hip_bf16.h>

#define DIMV 64
#define CH 64
#define EPSB 1e-3f

using bf16x8 = __attribute__((ext_vector_type(8))) short;
using f32x16 = __attribute__((ext_vector_type(16))) float;

__device__ __forceinline__ unsigned short f2bf(float f) {
    union { float f; unsigned u; } x; x.f = f;
    unsigned r = x.u + 0x7fff + ((x.u >> 16) & 1);   // round-to-nearest-even
    return (unsigned short)(r >> 16);
}
__device__ __forceinline__ float bf2f(unsigned short u) {
    union { unsigned u; float f; } x; x.u = ((unsigned)u) << 16;
    return x.f;
}

// ---------------- scatter: bf16 packed-atomic, inv folded in ----------------
// One thread per (point, channel-pair). Lanes 0..31 of a point cover c=0..63
// contiguously -> each atomic wavefront touches 2 contiguous 128B segments.
__global__ void scatter_bf16(const float* __restrict__ x, const int* __restrict__ idx,
                             const float* __restrict__ inv, unsigned short* __restrict__ grid,
                             int n2) {
    int tid = blockIdx.x * blockDim.x + threadIdx.x;
    if (tid >= n2) return;
    int n = tid >> 5, c2 = tid & 31;
    int ix = idx[n * 3 + 0], iy = idx[n * 3 + 1], iz = idx[n * 3 + 2];
    int vox = ((ix * DIMV) + iy) * DIMV + iz;
    float s = inv[vox];
    float v0 = x[(size_t)n * CH + c2 * 2 + 0] * s;
    float v1 = x[(size_t)n * CH + c2 * 2 + 1] * s;
    unsigned pk = (unsigned)f2bf(v0) | ((unsigned)f2bf(v1) << 16);
    unsigned short* addr = grid + (size_t)vox * CH + c2 * 2;
    asm volatile("global_atomic_pk_add_bf16 %0, %1, off" :: "v"(addr), "v"(pk) : "memory");
}

// ---------------- merged weight repack (k1, k2, w_mlp) into MFMA B-fragment layout ----------------
__global__ void wprep_all(const float* __restrict__ K1, const float* __restrict__ K2,
                          const float* __restrict__ Wm, unsigned short* __restrict__ wbuf1,
                          unsigned short* __restrict__ wbuf2, unsigned short* __restrict__ wm) {
    int t = blockIdx.x * 256 + threadIdx.x;
    if (t >= 2 * 110592 + 4096) return;
    const float* src;
    unsigned short* dst;
    int tt;
    if (t < 110592) { src = K1; dst = wbuf1; tt = t; }
    else if (t < 221184) { src = K2; dst = wbuf2; tt = t - 110592; }
    else { src = Wm; dst = wm; tt = t - 221184; }
    int j = tt & 7;
    int l = (tt >> 3) & 63;
    int nt = (tt >> 9) & 1;
    int kkl = (tt >> 10) & 3;
    int d = tt >> 12;                 // 0 for the mlp case
    int ci = kkl * 16 + (l >> 5) * 8 + j;
    int co = nt * 32 + (l & 31);
    dst[tt] = f2bf(src[((size_t)d * 64 + ci) * 64 + co]);
}

// ---------------- MFMA conv (r15-exact): 2x2x32 tile, 8 waves = (4 cols x 2 nt) ----------------
// Slab: 4x4 cols x 17 z-pairs x 256B = 69632 B -> 2 blocks/CU -> 4 waves/SIMD.
// Wave w: col = w>>1 (cx=bit1 of col... cx=(w>>2)&1, cy=(w>>1)&1), ntw = w&1.
// Per d-step per wave: 4 A ds_reads + 4 B loads -> 4 MFMAs. Proven 86.6us @ 52 VGPR.
__global__ __launch_bounds__(512) void conv_mfma(
    const unsigned short* __restrict__ G, const unsigned short* __restrict__ wbuf,
    const float* __restrict__ cb, const float* __restrict__ g,
    const float* __restrict__ be, const float* __restrict__ m,
    const float* __restrict__ v, unsigned short* __restrict__ out) {
    __shared__ __align__(16) unsigned short slab[272 * 128];   // 69632 B
    const int tid = threadIdx.x;
    const int lane = tid & 63;
    const int w = tid >> 6;          // wave 0..7
    const int cx = (w >> 2) & 1;     // col = w>>1: cx = bit1, cy = bit0
    const int cy = (w >> 1) & 1;
    const int ntw = w & 1;           // co half
    const int lz = lane & 31;
    const int kg = lane >> 5;
    const int BX = blockIdx.x, BY = blockIdx.y, BZ = blockIdx.z;
    const int x0 = 2 * BX - 1, y0 = 2 * BY - 1;
    const int zbase = 32 * BZ - 1;   // odd

    // Stage A slab: 4352 chunks of 16B. Pre-swizzled global source, linear LDS
    // write. Slot s at row (col,zp) holds ch-pair chunk cp = s ^ (zp&15).
#pragma unroll
    for (int it = 0; it < 9; ++it) {
        int idx = it * 512 + tid;
        if (idx < 4352) {
            int s = idx & 15;
            int r = idx >> 4;               // 0..271
            int zp = r % 17;
            int rxy = r / 17;               // 0..15
            int xx = x0 + (rxy >> 2);
            int yy = y0 + (rxy & 3);
            int cp = s ^ (zp & 15);
            int c = cp >> 1, p = cp & 1;
            int zz = zbase + 2 * zp + p;
            int4 val = make_int4(0, 0, 0, 0);
            if ((unsigned)xx < DIMV && (unsigned)yy < DIMV && (unsigned)zz < DIMV)
                val = *(const int4*)(G + (size_t)(((xx * DIMV) + yy) * DIMV + zz) * CH + c * 8);
            *(int4*)(slab + (size_t)idx * 8) = val;
        }
    }
    __syncthreads();

    f32x16 acc;
#pragma unroll
    for (int r = 0; r < 16; ++r) acc[r] = 0.f;

    // B ping-pong prefetch: frag kkl at wbuf + d*4096 + kkl*1024 + ntw*512 + lane*8
    bf16x8 bfr0[4], bfr1[4];
#pragma unroll
    for (int q = 0; q < 4; ++q)
        bfr0[q] = *(const bf16x8*)(wbuf + q * 1024 + ntw * 512 + lane * 8);

#pragma unroll
    for (int d = 0; d < 27; ++d) {
        if (d < 26) {
            const unsigned short* wn = wbuf + (size_t)(d + 1) * 4096 + ntw * 512 + lane * 8;
            if (d & 1) {
#pragma unroll
                for (int q = 0; q < 4; ++q) bfr0[q] = *(const bf16x8*)(wn + q * 1024);
            } else {
#pragma unroll
                for (int q = 0; q < 4; ++q) bfr1[q] = *(const bf16x8*)(wn + q * 1024);
            }
        }
        const int dx = d / 9, dy = (d / 3) % 3, dz = d % 3;
        const int zval = lz + dz;                  // 0..33
        const int zp = zval >> 1, p = zval & 1;
        const int rbase = ((cx + dx) * 4 + (cy + dy)) * 17 + zp;
#pragma unroll
        for (int kkl = 0; kkl < 4; ++kkl) {
            const int c = kkl * 2 + kg;
            const int slot = (c * 2 + p) ^ (zp & 15);
            bf16x8 a = *(const bf16x8*)(slab + rbase * 128 + slot * 8);
            bf16x8 b = (d & 1) ? bfr1[kkl] : bfr0[kkl];
            acc = __builtin_amdgcn_mfma_f32_32x32x16_bf16(a, b, acc, 0, 0, 0);
        }
    }

    const int x_out = 2 * BX + cx;
    const int y_out = 2 * BY + cy;
    const int co = ntw * 32 + lz;
    float scale = g[co] * rsqrtf(v[co] + EPSB);
    float shift = be[co] - m[co] * scale;
    float bias = cb[co];
    size_t base = (size_t)((x_out * DIMV) + y_out) * DIMV * CH + co;
#pragma unroll
    for (int r = 0; r < 16; ++r) {
        int zrow = (r & 3) + 8 * (r >> 2) + 4 * kg;
        int z = BZ * 32 + zrow;
        float val = fmaxf(acc[r] + bias, 0.f) * scale + shift;
        out[base + (size_t)z * CH] = f2bf(val);
    }
}

// ---------------- fused point-MLP (MFMA) + trilinear gather + final write ----------------
__global__ __launch_bounds__(256) void mlp_gather(
    const float* __restrict__ x, const unsigned short* __restrict__ wfrag,
    const float* __restrict__ b, const float* __restrict__ g,
    const float* __restrict__ be, const float* __restrict__ m,
    const float* __restrict__ v, const unsigned short* __restrict__ grid,
    const float* __restrict__ pts, float* __restrict__ out, int npts) {
    __shared__ float lds[128 * 64];          // 32 KB
    const int w = threadIdx.x >> 6;
    const int lane = threadIdx.x & 63;
    const int col = lane & 31;
    const int kg = lane >> 5;
    const int p0 = (blockIdx.x * 4 + w) * 32;

    if (p0 < npts) {
        bf16x8 a[4];
        const float* xr = x + (size_t)(p0 + col) * CH + kg * 8;
#pragma unroll
        for (int kk = 0; kk < 4; ++kk) {
            const float* p = xr + kk * 16;
            bf16x8 t;
#pragma unroll
            for (int j = 0; j < 8; ++j) t[j] = (short)f2bf(p[j]);
            a[kk] = t;
        }
        f32x16 acc[2];
#pragma unroll
        for (int nt = 0; nt < 2; ++nt)
#pragma unroll
            for (int r = 0; r < 16; ++r) acc[nt][r] = 0.f;
#pragma unroll
        for (int kk = 0; kk < 4; ++kk) {
            bf16x8 b0 = *(const bf16x8*)(wfrag + (kk * 2 + 0) * 512 + lane * 8);
            bf16x8 b1 = *(const bf16x8*)(wfrag + (kk * 2 + 1) * 512 + lane * 8);
            acc[0] = __builtin_amdgcn_mfma_f32_32x32x16_bf16(a[kk], b0, acc[0], 0, 0, 0);
            acc[1] = __builtin_amdgcn_mfma_f32_32x32x16_bf16(a[kk], b1, acc[1], 0, 0, 0);
        }
#pragma unroll
        for (int nt = 0; nt < 2; ++nt) {
            int co = nt * 32 + col;
            float scale = g[co] * rsqrtf(v[co] + EPSB);
            float shift = be[co] - m[co] * scale;
            float bias = b[co];
#pragma unroll
            for (int r = 0; r < 16; ++r) {
                int row = (r & 3) + 8 * (r >> 2) + 4 * kg;
                float val = fmaxf(acc[nt][r] + bias, 0.f) * scale + shift;
                lds[(w * 32 + row) * 64 + co] = val;
            }
        }
    }
    __syncthreads();

    const int pblk = blockIdx.x * 128;
#pragma unroll 4
    for (int i = 0; i < 32; ++i) {
        int idx = i * 256 + threadIdx.x;
        int pl = idx >> 6;
        int c = idx & 63;
        int pt = pblk + pl;
        if (pt >= npts) break;
        float px = fminf(fmaxf(pts[pt * 3 + 0], 0.f), (float)(DIMV - 1));
        float py = fminf(fmaxf(pts[pt * 3 + 1], 0.f), (float)(DIMV - 1));
        float pz = fminf(fmaxf(pts[pt * 3 + 2], 0.f), (float)(DIMV - 1));
        float fx = floorf(px), fy = floorf(py), fz = floorf(pz);
        float tx = px - fx, ty = py - fy, tz = pz - fz;
        int x0 = (int)fx, y0 = (int)fy, z0 = (int)fz;
        int x1 = min(x0 + 1, DIMV - 1), y1 = min(y0 + 1, DIMV - 1), z1 = min(z0 + 1, DIMV - 1);
        float wx0 = 1.f - tx, wy0 = 1.f - ty, wz0 = 1.f - tz;
        float acc = lds[pl * 64 + c];
        acc = fmaf(wx0 * wy0 * wz0, bf2f(grid[(size_t)(((x0 * DIMV) + y0) * DIMV + z0) * CH + c]), acc);
        acc = fmaf(wx0 * wy0 * tz,  bf2f(grid[(size_t)(((x0 * DIMV) + y0) * DIMV + z1) * CH + c]), acc);
        acc = fmaf(wx0 * ty * wz0,  bf2f(grid[(size_t)(((x0 * DIMV) + y1) * DIMV + z0) * CH + c]), acc);
        acc = fmaf(wx0 * ty * tz,   bf2f(grid[(size_t)(((x0 * DIMV) + y1) * DIMV + z1) * CH + c]), acc);
        acc = fmaf(tx * wy0 * wz0,  bf2f(grid[(size_t)(((x1 * DIMV) + y0) * DIMV + z0) * CH + c]), acc);
        acc = fmaf(tx * wy0 * tz,   bf2f(grid[(size_t)(((x1 * DIMV) + y0) * DIMV + z1) * CH + c]), acc);
        acc = fmaf(tx * ty * wz0,   bf2f(grid[(size_t)(((x1 * DIMV) + y1) * DIMV + z0) * CH + c]), acc);
        acc = fmaf(tx * ty * tz,    bf2f(grid[(size_t)(((x1 * DIMV) + y1) * DIMV + z1) * CH + c]), acc);
        out[(size_t)pt * CH + c] = acc;
    }
}

extern "C" void kernel_launch(void* const* d_in, const int* in_sizes, int n_in,
                              void* d_out, int out_size, void* d_ws, size_t ws_size,
                              hipStream_t stream) {
    const float* inputs = (const float*)d_in[0];
    const float* pt_coords = (const float*)d_in[1];
    const int* voxel_indexes = (const int*)d_in[2];
    const float* ppvi = (const float*)d_in[3];
    const float* w_mlp = (const float*)d_in[4];
    const float* b_mlp = (const float*)d_in[5];
    const float* g0 = (const float*)d_in[6];
    const float* be0 = (const float*)d_in[7];
    const float* m0 = (const float*)d_in[8];
    const float* v0 = (const float*)d_in[9];
    const float* k1 = (const float*)d_in[10];
    const float* cb1 = (const float*)d_in[11];
    const float* g1 = (const float*)d_in[12];
    const float* be1 = (const float*)d_in[13];
    const float* m1 = (const float*)d_in[14];
    const float* v1 = (const float*)d_in[15];
    const float* k2 = (const float*)d_in[16];
    const float* cb2 = (const float*)d_in[17];
    const float* g2 = (const float*)d_in[18];
    const float* be2 = (const float*)d_in[19];
    const float* m2 = (const float*)d_in[20];
    const float* v2 = (const float*)d_in[21];
    float* out = (float*)d_out;

    char* ws = (char*)d_ws;
    // [0,33.5M):      G2 bf16 (conv1 out, conv2 in)
    // [33.5M,67.1M):  G3 bf16 (conv2 out, gather in)
    // [67.1M,100.7M): G1 bf16 (scatter target, conv1 in)
    // [100.7M, +):    wbuf1, wbuf2 (221184 B each), wmlp (8192 B)
    unsigned short* G2 = (unsigned short*)ws;
    unsigned short* G3 = (unsigned short*)(ws + 33554432);
    unsigned short* G1 = (unsigned short*)(ws + 67108864);
    unsigned short* wbuf1 = (unsigned short*)(ws + 100663296);
    unsigned short* wbuf2 = (unsigned short*)(ws + 100884480);
    unsigned short* wmlp = (unsigned short*)(ws + 101105664);

    const int n_total = in_sizes[0];           // N * C
    const int npts = n_total / CH;
    const int n2 = npts * 32;                  // (point, ch-pair) work items
    const size_t grid_elems = (size_t)DIMV * DIMV * DIMV * CH;

    hipMemsetAsync(G1, 0, grid_elems * sizeof(unsigned short), stream);
    wprep_all<<<880, 256, 0, stream>>>(k1, k2, w_mlp, wbuf1, wbuf2, wmlp);
    scatter_bf16<<<(n2 + 255) / 256, 256, 0, stream>>>(inputs, voxel_indexes, ppvi, G1, n2);

    dim3 cgrid(32, 32, 2);
    conv_mfma<<<cgrid, 512, 0, stream>>>(G1, wbuf1, cb1, g1, be1, m1, v1, G2);
    conv_mfma<<<cgrid, 512, 0, stream>>>(G2, wbuf2, cb2, g2, be2, m2, v2, G3);

    mlp_gather<<<(npts + 127) / 128, 256, 0, stream>>>(
        inputs, wmlp, b_mlp, g0, be0, m0, v0, G3, pt_coords, out, npts);
}